// Round 1
// baseline (1881.093 us; speedup 1.0000x reference)
//
#include <hip/hip_runtime.h>
#include <stdint.h>

// K-means cluster aggregator:
//   centers0 = nodes[center_ind]            [K, D]
//   assignment[i] = argmin_k ||c_k - x_i||^2  (first-min tie-break, like jnp.argmin)
//   out[k] = sum_{i: assignment[i]==k} nodes[i]
//
// Strategy (fp32 baseline, round 1):
//   Kernel 1: gather centers transposed into ws ([D][K]) + cent_sq[k] = ||c_k||^2
//   Kernel 2: GEMM-argmin: block = 128 nodes x 128 centers, 8x8 micro-tile/thread,
//             running best via packed (score,k) LDS atomicMin (duplicate centers are
//             bit-identical -> smallest k wins, matching reference tie-break),
//             then fused scatter via global atomicAdd.

#define BN  128   // nodes per block
#define BKC 128   // centers per tile
#define BD  16    // D-chunk

__global__ void gather_centers(const float* __restrict__ nodes,
                               const int* __restrict__ center_ind,
                               float* __restrict__ centersT,   // [D][K]
                               float* __restrict__ cent_sq,    // [K]
                               int K, int D) {
    int k = blockIdx.x;
    int ci = center_ind[k];
    const float4* row = reinterpret_cast<const float4*>(nodes + (size_t)ci * D);
    int nf4 = D >> 2;
    float ssq = 0.f;
    for (int f = (int)threadIdx.x; f < nf4; f += (int)blockDim.x) {
        float4 v = row[f];
        int d = f << 2;
        centersT[(size_t)(d + 0) * K + k] = v.x;
        centersT[(size_t)(d + 1) * K + k] = v.y;
        centersT[(size_t)(d + 2) * K + k] = v.z;
        centersT[(size_t)(d + 3) * K + k] = v.w;
        ssq += v.x * v.x + v.y * v.y + v.z * v.z + v.w * v.w;
    }
    // block reduce (blockDim = 128 -> 2 waves)
    for (int off = 32; off > 0; off >>= 1) ssq += __shfl_down(ssq, off, 64);
    __shared__ float partial[4];
    int wave = threadIdx.x >> 6, lane = threadIdx.x & 63;
    if (lane == 0) partial[wave] = ssq;
    __syncthreads();
    if (threadIdx.x == 0) {
        float t = 0.f;
        int nw = ((int)blockDim.x + 63) >> 6;
        for (int w = 0; w < nw; w++) t += partial[w];
        cent_sq[k] = t;
    }
}

__launch_bounds__(256, 2)
__global__ void assign_scatter(const float* __restrict__ nodes,
                               const float* __restrict__ centersT,  // [D][K]
                               const float* __restrict__ cent_sq,   // [K]
                               float* __restrict__ out,             // [K][D], pre-zeroed
                               int N, int D, int K) {
    __shared__ float ct[BD][BKC];            // center tile, transposed [d][k]
    __shared__ float nt[BD][BN];             // node tile, transposed [d][n]
    __shared__ unsigned long long best[BN];  // packed (orderable score << 32) | k

    const int tid = (int)threadIdx.x;
    const int n0  = (int)blockIdx.x * BN;
    const int tx  = tid & 15;   // node group
    const int ty  = tid >> 4;   // center group

    for (int i = tid; i < BN; i += 256) best[i] = ~0ULL;

    for (int kt = 0; kt < K; kt += BKC) {
        float acc[8][8];
        #pragma unroll
        for (int i = 0; i < 8; i++)
            #pragma unroll
            for (int j = 0; j < 8; j++) acc[i][j] = 0.f;

        for (int d0 = 0; d0 < D; d0 += BD) {
            __syncthreads();  // protect LDS tiles (prev compute / best init) before overwrite
            // stage center tile: contiguous along k -> fully coalesced
            #pragma unroll
            for (int i = 0; i < 2; i++) {
                int f  = tid + i * 256;       // 512 float4 total
                int d  = f >> 5;              // 32 float4 per d-row
                int kq = (f & 31) << 2;
                float4 v = *reinterpret_cast<const float4*>(
                    &centersT[(size_t)(d0 + d) * K + kt + kq]);
                *reinterpret_cast<float4*>(&ct[d][kq]) = v;
            }
            // stage node tile transposed: 4 lanes cover 64B of one row
            #pragma unroll
            for (int i = 0; i < 2; i++) {
                int f  = tid + i * 256;       // 512 float4 total
                int n  = f >> 2;              // 4 float4 per node row chunk
                int dq = (f & 3) << 2;
                int gn = n0 + n;
                float4 v = make_float4(0.f, 0.f, 0.f, 0.f);
                if (gn < N)
                    v = *reinterpret_cast<const float4*>(&nodes[(size_t)gn * D + d0 + dq]);
                nt[dq + 0][n] = v.x;
                nt[dq + 1][n] = v.y;
                nt[dq + 2][n] = v.z;
                nt[dq + 3][n] = v.w;
            }
            __syncthreads();
            #pragma unroll
            for (int d = 0; d < BD; d++) {
                float a[8], b[8];
                *reinterpret_cast<float4*>(&a[0]) = *reinterpret_cast<float4*>(&ct[d][ty * 8]);
                *reinterpret_cast<float4*>(&a[4]) = *reinterpret_cast<float4*>(&ct[d][ty * 8 + 4]);
                *reinterpret_cast<float4*>(&b[0]) = *reinterpret_cast<float4*>(&nt[d][tx * 8]);
                *reinterpret_cast<float4*>(&b[4]) = *reinterpret_cast<float4*>(&nt[d][tx * 8 + 4]);
                #pragma unroll
                for (int i = 0; i < 8; i++)
                    #pragma unroll
                    for (int j = 0; j < 8; j++)
                        acc[i][j] = fmaf(a[i], b[j], acc[i][j]);
            }
        }

        // local argmin per node (ascending k, strict <), then packed LDS atomicMin.
        // score = ||c||^2 - 2*dot  (node_sq is a per-node constant shift; irrelevant
        // to argmin AND preserves tie structure). Duplicate centers are computed by the
        // identical instruction sequence -> bit-identical -> min picks smallest k.
        float csq[8];
        #pragma unroll
        for (int i = 0; i < 8; i++) csq[i] = cent_sq[kt + ty * 8 + i];
        #pragma unroll
        for (int j = 0; j < 8; j++) {
            float bv = __builtin_inff();
            int   bi = 0;
            #pragma unroll
            for (int i = 0; i < 8; i++) {
                float s = fmaf(-2.f, acc[i][j], csq[i]);
                if (s < bv) { bv = s; bi = i; }
            }
            unsigned ub = __float_as_uint(bv);
            ub = (ub & 0x80000000u) ? ~ub : (ub | 0x80000000u);  // orderable fp32
            unsigned kk = (unsigned)(kt + ty * 8 + bi);
            unsigned long long pk = ((unsigned long long)ub << 32) | kk;
            atomicMin(&best[tx * 8 + j], pk);
        }
    }
    __syncthreads();

    // fused scatter: whole block streams each of its nodes into out[assignment]
    for (int n = 0; n < BN; n++) {
        int gn = n0 + n;
        if (gn >= N) break;
        int k = (int)(best[n] & 0xFFFFFFFFu);
        const float* row = nodes + (size_t)gn * D;
        float* dst = out + (size_t)k * D;
        for (int d = tid; d < D; d += 256)
            atomicAdd(&dst[d], row[d]);
    }
}

extern "C" void kernel_launch(void* const* d_in, const int* in_sizes, int n_in,
                              void* d_out, int out_size, void* d_ws, size_t ws_size,
                              hipStream_t stream) {
    const float* nodes      = (const float*)d_in[0];
    const int*   center_ind = (const int*)d_in[1];
    // num_clusters (d_in[2]) is a device scalar; K is also the length of center_ind.
    int K = in_sizes[1];
    int D = out_size / K;          // 512
    int N = in_sizes[0] / D;       // 100000

    float* centersT = (float*)d_ws;                  // D*K floats (2 MB)
    float* cent_sq  = centersT + (size_t)D * K;      // K floats
    float* out      = (float*)d_out;

    // Harness poisons d_out once and never re-zeroes between replays.
    hipMemsetAsync(out, 0, (size_t)out_size * sizeof(float), stream);

    gather_centers<<<K, 128, 0, stream>>>(nodes, center_ind, centersT, cent_sq, K, D);

    int nblk = (N + BN - 1) / BN;
    assign_scatter<<<nblk, 256, 0, stream>>>(nodes, centersT, cent_sq, out, N, D, K);
}

// Round 2
// 852.455 us; speedup vs baseline: 2.2067x; 2.2067x over previous
//
#include <hip/hip_runtime.h>
#include <stdint.h>

// K-means cluster aggregator, round 2: f16 MFMA scores + ballot-scan aggregation.
//   scores: s[k,i] = ||c_k||^2 - 2 * <c_k, x_i>   (node_sq shift irrelevant to argmin)
//   dot via mfma_f32_16x16x32_f16 (inputs f16, accum fp32).
//   Tie-break: packed (orderable_score<<32 | k) min -> smallest k on bit-equal scores;
//   duplicate centers have identical f16 rows + identical fp32 csq -> bit-identical scores.

typedef _Float16 f16x8 __attribute__((ext_vector_type(8)));
typedef float    f32x4 __attribute__((ext_vector_type(4)));

#define DD 512   // feature dim (fixed by problem)

static __device__ __forceinline__ unsigned orderable(float s) {
    unsigned u = __float_as_uint(s);
    return (u & 0x80000000u) ? ~u : (u | 0x80000000u);
}

// ---- kernel 1: gather centers -> f16 rows in ws + fp32 ||c||^2 -----------------
__global__ void gather_centers(const float* __restrict__ nodes,
                               const int* __restrict__ center_ind,
                               _Float16* __restrict__ cent16,   // [K][DD]
                               float* __restrict__ cent_sq,     // [K]
                               int K) {
    int k    = (int)blockIdx.x;
    int lane = (int)threadIdx.x;                 // 64
    int ci   = center_ind[k];
    const f32x4* p = reinterpret_cast<const f32x4*>(nodes + (size_t)ci * DD + lane * 8);
    f32x4 v0 = p[0], v1 = p[1];
    f16x8 h;
    h[0]=(_Float16)v0[0]; h[1]=(_Float16)v0[1]; h[2]=(_Float16)v0[2]; h[3]=(_Float16)v0[3];
    h[4]=(_Float16)v1[0]; h[5]=(_Float16)v1[1]; h[6]=(_Float16)v1[2]; h[7]=(_Float16)v1[3];
    *reinterpret_cast<f16x8*>(cent16 + (size_t)k * DD + lane * 8) = h;
    float ssq = v0[0]*v0[0]+v0[1]*v0[1]+v0[2]*v0[2]+v0[3]*v0[3]
              + v1[0]*v1[0]+v1[1]*v1[1]+v1[2]*v1[2]+v1[3]*v1[3];
    #pragma unroll
    for (int off = 32; off > 0; off >>= 1) ssq += __shfl_xor(ssq, off, 64);
    if (lane == 0) cent_sq[k] = ssq;             // same reduce order for every k ->
                                                 // duplicate ci gives bit-identical csq
}

// ---- kernel 2: MFMA assign --------------------------------------------------------
// block: 64 nodes, 256 threads (4 waves); wave w owns centers [w*K/4, (w+1)*K/4).
__launch_bounds__(256, 2)
__global__ void assign_mfma(const float* __restrict__ nodes,
                            const _Float16* __restrict__ cent16,  // [K][DD]
                            const float* __restrict__ cent_sq,    // [K]
                            unsigned* __restrict__ assignment,    // [N]
                            int N, int K) {
    __shared__ __align__(16) _Float16 nt[64 * DD];       // 64 KB, XOR-swizzled
    __shared__ float csq[1024];
    __shared__ unsigned long long best[64];

    const int tid = (int)threadIdx.x;
    const int n0  = (int)blockIdx.x * 64;

    // stage node tile -> f16 LDS (once per block). One wave per row chunk set:
    // f = it*256+tid: row = f>>6 (uniform per wave), dchunk = f&63 -> conflict-free writes.
    #pragma unroll
    for (int it = 0; it < 16; ++it) {
        int f   = it * 256 + tid;
        int row = f >> 6;
        int d0  = (f & 63) << 3;
        f32x4 v0 = {0.f,0.f,0.f,0.f}, v1 = {0.f,0.f,0.f,0.f};
        if (n0 + row < N) {
            const f32x4* p = reinterpret_cast<const f32x4*>(nodes + (size_t)(n0 + row) * DD + d0);
            v0 = p[0]; v1 = p[1];
        }
        f16x8 h;
        h[0]=(_Float16)v0[0]; h[1]=(_Float16)v0[1]; h[2]=(_Float16)v0[2]; h[3]=(_Float16)v0[3];
        h[4]=(_Float16)v1[0]; h[5]=(_Float16)v1[1]; h[6]=(_Float16)v1[2]; h[7]=(_Float16)v1[3];
        int byte = ((row << 10) + (d0 << 1)) ^ ((row & 7) << 4);
        *reinterpret_cast<f16x8*>(reinterpret_cast<char*>(nt) + byte) = h;
    }
    for (int j = tid; j < K;  j += 256) csq[j]  = cent_sq[j];
    for (int j = tid; j < 64; j += 256) best[j] = ~0ULL;
    __syncthreads();

    const int lane = tid & 63;
    const int wid  = tid >> 6;
    const int l15  = lane & 15;
    const int g    = lane >> 4;          // quarter group (k-slice / C-row group)
    const int g8   = g * 8;
    const int swz  = (l15 & 7) << 4;     // row&7 == l15&7 (rows are nG*16 + l15)
    const int cPerWave = K >> 2;
    const int cw0  = wid * cPerWave;
    char* ntb = reinterpret_cast<char*>(nt);

    int bbase[4];
    #pragma unroll
    for (int nG = 0; nG < 4; ++nG) bbase[nG] = (((nG * 16 + l15) << 10) + (g << 4));

    const int nT = cPerWave >> 6;        // 64-center tiles per wave
    for (int t64 = 0; t64 < nT; ++t64) {
        const int cbase = cw0 + t64 * 64;
        f32x4 acc[4][4];                 // [center subtile][node group]
        #pragma unroll
        for (int a = 0; a < 4; ++a)
            #pragma unroll
            for (int b = 0; b < 4; ++b) { f32x4 z = {0.f,0.f,0.f,0.f}; acc[a][b] = z; }

        #pragma unroll 2
        for (int d0 = 0; d0 < DD; d0 += 32) {
            f16x8 A[4], B[4];
            #pragma unroll
            for (int tC = 0; tC < 4; ++tC)   // A: lane l -> row l&15, k = g*8+j (contig 16B)
                A[tC] = *reinterpret_cast<const f16x8*>(
                    cent16 + ((size_t)(cbase + tC * 16 + l15) << 9) + d0 + g8);
            #pragma unroll
            for (int nG = 0; nG < 4; ++nG)   // B: lane l -> col l&15, k = g*8+j (swizzled LDS)
                B[nG] = *reinterpret_cast<const f16x8*>(
                    ntb + ((bbase[nG] + (d0 << 1)) ^ swz));
            #pragma unroll
            for (int tC = 0; tC < 4; ++tC)
                #pragma unroll
                for (int nG = 0; nG < 4; ++nG)
                    acc[tC][nG] = __builtin_amdgcn_mfma_f32_16x16x32_f16(
                        A[tC], B[nG], acc[tC][nG], 0, 0, 0);
        }

        // epilogue: score = csq - 2*dot; packed min (smallest k on ties)
        #pragma unroll
        for (int nG = 0; nG < 4; ++nG) {
            unsigned long long pk = ~0ULL;
            #pragma unroll
            for (int tC = 0; tC < 4; ++tC) {
                #pragma unroll
                for (int q = 0; q < 4; ++q) {
                    int c = cbase + tC * 16 + g * 4 + q;   // C-row = g*4+q
                    float s = fmaf(-2.f, acc[tC][nG][q], csq[c]);
                    unsigned long long v =
                        ((unsigned long long)orderable(s) << 32) | (unsigned)c;
                    pk = v < pk ? v : pk;
                }
            }
            unsigned long long o;
            o = __shfl_xor(pk, 16, 64); pk = o < pk ? o : pk;
            o = __shfl_xor(pk, 32, 64); pk = o < pk ? o : pk;
            if (lane < 16) atomicMin(&best[nG * 16 + l15], pk);
        }
    }
    __syncthreads();
    if (tid < 64 && n0 + tid < N)
        assignment[n0 + tid] = (unsigned)(best[tid] & 0xffffffffu);
}

// ---- kernel 3: per-cluster ballot-scan aggregation (no atomics) -------------------
__launch_bounds__(256, 4)
__global__ void aggregate(const float* __restrict__ nodes,
                          const unsigned* __restrict__ assignment,
                          float* __restrict__ out, int N) {
    const int k    = (int)blockIdx.x;
    const int tid  = (int)threadIdx.x;
    const int wid  = tid >> 6;
    const int lane = tid & 63;
    f32x4 a0 = {0.f,0.f,0.f,0.f}, a1 = {0.f,0.f,0.f,0.f};   // dims lane*8 .. lane*8+7

    for (int base = wid * 64; base < N; base += 256) {
        int i = base + lane;
        bool m = (i < N) && (assignment[i] == (unsigned)k);
        unsigned long long mask = __ballot(m);
        while (mask) {
            int b = __ffsll((long long)mask) - 1;
            mask &= mask - 1;
            const f32x4* p = reinterpret_cast<const f32x4*>(
                nodes + (size_t)(base + b) * DD + lane * 8);
            f32x4 v0 = p[0], v1 = p[1];
            a0 += v0; a1 += v1;
        }
    }
    __shared__ float sums[4][DD];
    *reinterpret_cast<f32x4*>(&sums[wid][lane * 8])     = a0;
    *reinterpret_cast<f32x4*>(&sums[wid][lane * 8 + 4]) = a1;
    __syncthreads();
    for (int d = tid; d < DD; d += 256)
        out[(size_t)k * DD + d] = (sums[0][d] + sums[1][d]) + (sums[2][d] + sums[3][d]);
}

extern "C" void kernel_launch(void* const* d_in, const int* in_sizes, int n_in,
                              void* d_out, int out_size, void* d_ws, size_t ws_size,
                              hipStream_t stream) {
    const float* nodes      = (const float*)d_in[0];
    const int*   center_ind = (const int*)d_in[1];
    int K = in_sizes[1];                  // 1024
    int D = out_size / K;                 // 512 (DD)
    int N = in_sizes[0] / D;              // 100000
    (void)D;

    char* ws = (char*)d_ws;
    _Float16* cent16     = (_Float16*)ws;                         // K*DD*2 = 1 MB
    float*    cent_sq    = (float*)(ws + (size_t)K * DD * 2);     // K*4
    unsigned* assignment = (unsigned*)(ws + (size_t)K * DD * 2 + (size_t)K * 4);  // N*4

    gather_centers<<<K, 64, 0, stream>>>(nodes, center_ind, cent16, cent_sq, K);
    assign_mfma<<<(N + 63) / 64, 256, 0, stream>>>(nodes, cent16, cent_sq, assignment, N, K);
    aggregate<<<K, 256, 0, stream>>>(nodes, assignment, out_size ? (float*)d_out : nullptr, N);
}